// Round 10
// baseline (1428.976 us; speedup 1.0000x reference)
//
#include <hip/hip_runtime.h>
#include <hip/hip_bf16.h>
#include <stdint.h>

#define NN 100000
#define NE 1600000

typedef __attribute__((ext_vector_type(4))) float f32x4;
typedef __attribute__((ext_vector_type(8))) __bf16 bf16x8;
typedef __attribute__((ext_vector_type(8))) short s16x8;
typedef __attribute__((ext_vector_type(4))) unsigned int u32x4;

__device__ __forceinline__ unsigned short f2bf(float f) {
  unsigned int u = __builtin_bit_cast(unsigned int, f);
  u += 0x7fffu + ((u >> 16) & 1u);
  return (unsigned short)(u >> 16);
}

__device__ __forceinline__ f32x4 mfma16(bf16x8 a, bf16x8 b, f32x4 c) {
  return __builtin_amdgcn_mfma_f32_16x16x32_bf16(a, b, c, 0, 0, 0);
}

// ---------------------------------------------------------------------------
// setup: node_state -> bf16 table; msg weights + global -> bf16
// ---------------------------------------------------------------------------
__global__ void convert_kernel(const float* __restrict__ ns,
                               const float* __restrict__ w1, const float* __restrict__ w2,
                               const float* __restrict__ g,
                               unsigned short* __restrict__ node_bf,
                               unsigned short* __restrict__ w1b, unsigned short* __restrict__ w2b,
                               unsigned short* __restrict__ gb)
{
  const int tid = blockIdx.x * 256 + threadIdx.x;
  const int stride = gridDim.x * 256;
  for (int i = tid; i < NN * 128; i += stride) node_bf[i] = f2bf(ns[i]);
  if (tid < 256 * 128) w1b[tid] = f2bf(w1[tid]);
  if (tid < 128 * 128) w2b[tid] = f2bf(w2[tid]);
  if (tid < 64) gb[tid] = f2bf(g[tid]);
}

// ---------------------------------------------------------------------------
// edge kernel: msg = MLP(concat(node_bf[src], edge_state, gs)) via bf16 MFMA;
// scatter: packed-bf16 atomics (global_atomic_pk_add_bf16) -> 2 cols/op,
// halving atomic op count (205M -> 102M) and atomic write payload.
// Precision precedent: r5-r8 passed (absmax 0.03125) with fp8-quantized
// messages -- coarser than bf16 pair + bf16 accumulation added here.
// ---------------------------------------------------------------------------
__global__ __launch_bounds__(256, 4) void edge_kernel(
    const int* __restrict__ ei,
    const float* __restrict__ edge_state,
    const unsigned short* __restrict__ node_bf,
    const unsigned short* __restrict__ w1b,
    const unsigned short* __restrict__ w2b,
    const float* __restrict__ bias1g,
    const float* __restrict__ bias2g,
    const unsigned short* __restrict__ gb,
    unsigned short* __restrict__ agg,   // bf16 [NN][128]
    float* __restrict__ deg)
{
  __shared__ unsigned short sX[64 * 256];  // 32 KB staging; front 16 KB reused as h1 tile
  __shared__ int sDst[64];
  unsigned short* sH = sX;                 // h1 [64][128] swizzled, aliases sX bytes 0..16K

  const int t = threadIdx.x;
  const int lane = t & 63;
  const int wv = t >> 6;
  const int l15 = lane & 15;
  const int lq = lane >> 4;

  // preload W1/W2 B-fragments (per-wave column slice)
  bf16x8 b1f[8][2], b2f[4][2];
  float bs1[2], bs2[2];
  for (int n = 0; n < 2; ++n) {
    const int col = wv * 32 + n * 16 + l15;
    bs1[n] = bias1g[col];
    bs2[n] = bias2g[col];
    for (int ks = 0; ks < 8; ++ks) {
      const int k0 = ks * 32 + lq * 8;
      s16x8 v;
#pragma unroll
      for (int j = 0; j < 8; ++j) v[j] = (short)w1b[(k0 + j) * 128 + col];
      b1f[ks][n] = __builtin_bit_cast(bf16x8, v);
    }
    for (int ks = 0; ks < 4; ++ks) {
      const int k0 = ks * 32 + lq * 8;
      s16x8 v;
#pragma unroll
      for (int j = 0; j < 8; ++j) v[j] = (short)w2b[(k0 + j) * 128 + col];
      b2f[ks][n] = __builtin_bit_cast(bf16x8, v);
    }
  }

  const int r = t >> 2;   // edge row within tile
  const int p = t & 3;    // quarter of the row
  const int rs = r & 7;   // swizzle key

  u32x4 gR0, gR1;
  {
    const u32x4* g = (const u32x4*)(gb + p * 16);
    gR0 = g[0]; gR1 = g[1];
  }

  const int grid = gridDim.x;
  const int NT = NE / 64;

  // ---- prologue: gather tile0; indices for tile1 ----
  u32x4 pfN[4];
  f32x4 pfE[4];
  int srcNext, dstNext, dstCur;
  {
    const int e0 = blockIdx.x * 64 + r;
    const int s0 = ei[e0];
    dstCur = ei[NE + e0];
    const u32x4* nb = (const u32x4*)(node_bf + (size_t)s0 * 128);
    const f32x4* es = (const f32x4*)(edge_state + (size_t)e0 * 64);
#pragma unroll
    for (int j = 0; j < 4; ++j) { pfN[j] = nb[p * 4 + j]; pfE[j] = es[p * 4 + j]; }
    const int e1 = min((blockIdx.x + grid) * 64 + r, NE - 1);
    srcNext = ei[e1];
    dstNext = ei[NE + e1];
  }

  for (int tile = blockIdx.x; tile < NT; tile += grid) {
    __syncthreads();  // prior iteration's phase-2 reads of sH (sX front) done

    // ---- stage: pure reg -> LDS ----
    if (p == 0) {
      sDst[r] = dstCur;
      atomicAdd(&deg[dstCur], 1.0f);
    }
#pragma unroll
    for (int j = 0; j < 4; ++j) {   // node chunks 0..15 (bf16)
      const int c = p * 4 + j;
      *(u32x4*)((char*)sX + r * 512 + ((c ^ rs) * 16)) = pfN[j];
    }
    {  // edge chunks 16..23 (f32 -> bf16)
      unsigned short bufa[8], bufb[8];
#pragma unroll
      for (int i = 0; i < 4; ++i) {
        bufa[i] = f2bf(pfE[0][i]); bufa[4 + i] = f2bf(pfE[1][i]);
        bufb[i] = f2bf(pfE[2][i]); bufb[4 + i] = f2bf(pfE[3][i]);
      }
      const int c = 16 + 2 * p;
      *(u32x4*)((char*)sX + r * 512 + ((c ^ rs) * 16)) = *(u32x4*)bufa;
      *(u32x4*)((char*)sX + r * 512 + (((c + 1) ^ rs) * 16)) = *(u32x4*)bufb;
    }
    {  // global chunks 24..31
      const int c = 24 + 2 * p;
      *(u32x4*)((char*)sX + r * 512 + ((c ^ rs) * 16)) = gR0;
      *(u32x4*)((char*)sX + r * 512 + (((c + 1) ^ rs) * 16)) = gR1;
    }
    __syncthreads();

    // ---- issue next tile's gathers (latency hidden under MFMA phases) ----
    {
      const int tn = tile + grid;
      const int eN = min(tn * 64 + r, NE - 1);
      const u32x4* nb = (const u32x4*)(node_bf + (size_t)srcNext * 128);
      const f32x4* es = (const f32x4*)(edge_state + (size_t)eN * 64);
#pragma unroll
      for (int j = 0; j < 4; ++j) { pfN[j] = nb[p * 4 + j]; pfE[j] = es[p * 4 + j]; }
      dstCur = dstNext;
      const int e2 = min((tn + grid) * 64 + r, NE - 1);
      srcNext = ei[e2];
      dstNext = ei[NE + e2];
    }

    // ---- phase 1: h1 = relu(X @ W1 + b1) ----
    f32x4 acc[4][2];
#pragma unroll
    for (int m = 0; m < 4; ++m)
#pragma unroll
      for (int n = 0; n < 2; ++n)
        acc[m][n] = (f32x4){bs1[n], bs1[n], bs1[n], bs1[n]};
#pragma unroll
    for (int ks = 0; ks < 8; ++ks) {
      bf16x8 a[4];
#pragma unroll
      for (int m = 0; m < 4; ++m) {
        const int row = m * 16 + l15;
        a[m] = *(const bf16x8*)((const char*)sX + row * 512 + (((4 * ks + lq) ^ (row & 7)) * 16));
      }
#pragma unroll
      for (int m = 0; m < 4; ++m)
#pragma unroll
        for (int n = 0; n < 2; ++n)
          acc[m][n] = mfma16(a[m], b1f[ks][n], acc[m][n]);
    }
    __syncthreads();  // all phase-1 sX reads done before overwriting sX front with h1

    // relu + store h1 (swizzled bf16 [64][128]) into sX front
#pragma unroll
    for (int m = 0; m < 4; ++m)
#pragma unroll
      for (int n = 0; n < 2; ++n)
#pragma unroll
        for (int i = 0; i < 4; ++i) {
          const int row = m * 16 + lq * 4 + i;
          const int col = wv * 32 + n * 16 + l15;
          float v = acc[m][n][i];
          v = v > 0.f ? v : 0.f;
          *(unsigned short*)((char*)sH + row * 256 +
                             ((((col >> 3) ^ (row & 7)) * 16) + (col & 7) * 2)) = f2bf(v);
        }
    __syncthreads();

    // ---- phase 2: msg = h1 @ W2 + b2; packed-bf16 atomic scatter ----
    f32x4 acc2[4][2];
#pragma unroll
    for (int m = 0; m < 4; ++m)
#pragma unroll
      for (int n = 0; n < 2; ++n)
        acc2[m][n] = (f32x4){bs2[n], bs2[n], bs2[n], bs2[n]};
#pragma unroll
    for (int ks = 0; ks < 4; ++ks) {
      bf16x8 a[4];
#pragma unroll
      for (int m = 0; m < 4; ++m) {
        const int row = m * 16 + l15;
        a[m] = *(const bf16x8*)((const char*)sH + row * 256 + (((4 * ks + lq) ^ (row & 7)) * 16));
      }
#pragma unroll
      for (int m = 0; m < 4; ++m)
#pragma unroll
        for (int n = 0; n < 2; ++n)
          acc2[m][n] = mfma16(a[m], b2f[ks][n], acc2[m][n]);
    }
    // column pairs live in adjacent lanes (col = l15): exchange via shfl_xor(1);
    // even lane emits rows i=0,1 of the pair, odd lane rows i=2,3.
    {
      const bool evenLane = (l15 & 1) == 0;
#pragma unroll
      for (int m = 0; m < 4; ++m)
#pragma unroll
        for (int n = 0; n < 2; ++n) {
          float pv[4];
#pragma unroll
          for (int i = 0; i < 4; ++i) pv[i] = __shfl_xor(acc2[m][n][i], 1);
          const int colBase = wv * 32 + n * 16 + (l15 & ~1);
#pragma unroll
          for (int i2 = 0; i2 < 2; ++i2) {
            const int i = evenLane ? i2 : 2 + i2;
            const int row = m * 16 + lq * 4 + i;
            const int d = sDst[row];
            const float v0 = evenLane ? acc2[m][n][i] : pv[i];
            const float v1 = evenLane ? pv[i] : acc2[m][n][i];
            const unsigned int pk =
                (unsigned int)f2bf(v0) | ((unsigned int)f2bf(v1) << 16);
            unsigned short* ap = agg + (size_t)d * 128 + colBase;
            asm volatile("global_atomic_pk_add_bf16 %0, %1, off"
                         :: "v"(ap), "v"(pk) : "memory");
          }
        }
    }
  }
}

// ---------------------------------------------------------------------------
// update MLP phase 1 in full f32 (VALU): h1 = relu(X @ U1 + b1), K = 320
// agg input is bf16 (decoded in-register)
// ---------------------------------------------------------------------------
__global__ __launch_bounds__(128, 3) void upd1_kernel(
    const float* __restrict__ node_state,
    const unsigned short* __restrict__ aggv,   // bf16 [NN][128]
    const float* __restrict__ deg,
    const float* __restrict__ u1,    // [320][128] f32
    const float* __restrict__ b1,
    const float* __restrict__ gs,    // [64] f32
    float* __restrict__ h1out)
{
  const int n = blockIdx.x * 128 + threadIdx.x;
  const bool act = n < NN;
  const size_t row = (size_t)(act ? n : 0) * 128;

  f32x4 acc[32];
#pragma unroll
  for (int c = 0; c < 32; ++c) acc[c] = *(const f32x4*)(b1 + 4 * c);

  const float rdeg = act ? (1.0f / fmaxf(deg[n], 1.0f)) : 0.0f;

  // node part: k = 0..127
  for (int k4 = 0; k4 < 32; ++k4) {
    const f32x4 x = *(const f32x4*)(node_state + row + 4 * k4);
#pragma unroll
    for (int kk = 0; kk < 4; ++kk) {
      const float xk = x[kk];
      const float* wr = u1 + (size_t)(4 * k4 + kk) * 128;
#pragma unroll
      for (int c = 0; c < 32; ++c) acc[c] += xk * *(const f32x4*)(wr + 4 * c);
    }
  }
  // aggregated part (bf16): k = 128..255
  {
    const u32x4* ab = (const u32x4*)(aggv + row);
    for (int k8 = 0; k8 < 16; ++k8) {
      const u32x4 w = ab[k8];
#pragma unroll
      for (int q = 0; q < 4; ++q) {
        const float x0 = __builtin_bit_cast(float, (w[q] & 0xffffu) << 16) * rdeg;
        const float x1 = __builtin_bit_cast(float, w[q] & 0xffff0000u) * rdeg;
        const float* wr0 = u1 + (size_t)(128 + k8 * 8 + 2 * q) * 128;
        const float* wr1 = wr0 + 128;
#pragma unroll
        for (int c = 0; c < 32; ++c) acc[c] += x0 * *(const f32x4*)(wr0 + 4 * c);
#pragma unroll
        for (int c = 0; c < 32; ++c) acc[c] += x1 * *(const f32x4*)(wr1 + 4 * c);
      }
    }
  }
  // global part: k = 256..319 (uniform xk)
  for (int k = 0; k < 64; ++k) {
    const float xk = gs[k];
    const float* wr = u1 + (size_t)(256 + k) * 128;
#pragma unroll
    for (int c = 0; c < 32; ++c) acc[c] += xk * *(const f32x4*)(wr + 4 * c);
  }

  if (act) {
    float* o = h1out + (size_t)n * 128;
#pragma unroll
    for (int c = 0; c < 32; ++c) {
      f32x4 v = acc[c];
#pragma unroll
      for (int i = 0; i < 4; ++i) v[i] = v[i] > 0.f ? v[i] : 0.f;
      *(f32x4*)(o + 4 * c) = v;
    }
  }
}

// ---------------------------------------------------------------------------
// update MLP phase 2 + residual + LayerNorm, full f32 (VALU)
// ---------------------------------------------------------------------------
__global__ __launch_bounds__(128, 3) void upd2_kernel(
    const float* __restrict__ node_state,
    const float* __restrict__ h1,
    const float* __restrict__ u2,    // [128][128] f32
    const float* __restrict__ b2,
    const float* __restrict__ lng,
    const float* __restrict__ lnb,
    float* __restrict__ out)
{
  const int n = blockIdx.x * 128 + threadIdx.x;
  const bool act = n < NN;
  const size_t row = (size_t)(act ? n : 0) * 128;

  f32x4 acc[32];
#pragma unroll
  for (int c = 0; c < 32; ++c) acc[c] = *(const f32x4*)(b2 + 4 * c);

  for (int k4 = 0; k4 < 32; ++k4) {
    const f32x4 h = *(const f32x4*)(h1 + row + 4 * k4);
#pragma unroll
    for (int kk = 0; kk < 4; ++kk) {
      const float hk = h[kk];
      const float* wr = u2 + (size_t)(4 * k4 + kk) * 128;
#pragma unroll
      for (int c = 0; c < 32; ++c) acc[c] += hk * *(const f32x4*)(wr + 4 * c);
    }
  }

  if (act) {
    float s = 0.f, s2 = 0.f;
#pragma unroll
    for (int c = 0; c < 32; ++c) {
      const f32x4 nd = *(const f32x4*)(node_state + row + 4 * c);
      f32x4 x = nd + acc[c];
      acc[c] = x;
#pragma unroll
      for (int i = 0; i < 4; ++i) { s += x[i]; s2 += x[i] * x[i]; }
    }
    const float mu = s * (1.0f / 128.0f);
    float var = s2 * (1.0f / 128.0f) - mu * mu;
    var = var < 0.f ? 0.f : var;
    const float rstd = rsqrtf(var + 1e-5f);
    float* o = out + (size_t)n * 128;
#pragma unroll
    for (int c = 0; c < 32; ++c) {
      const f32x4 g = *(const f32x4*)(lng + 4 * c);
      const f32x4 b = *(const f32x4*)(lnb + 4 * c);
      f32x4 x = acc[c];
#pragma unroll
      for (int i = 0; i < 4; ++i) x[i] = (x[i] - mu) * rstd * g[i] + b[i];
      *(f32x4*)(o + 4 * c) = x;
    }
  }
}

// ---------------------------------------------------------------------------
extern "C" void kernel_launch(void* const* d_in, const int* in_sizes, int n_in,
                              void* d_out, int out_size, void* d_ws, size_t ws_size,
                              hipStream_t stream)
{
  const float* node_state = (const float*)d_in[0];
  const int* ei           = (const int*)d_in[1];   // int64 in reference -> int32 from harness
  const float* edge_state = (const float*)d_in[2];
  const float* gstate     = (const float*)d_in[3];
  const float* msg_w1     = (const float*)d_in[4];
  const float* msg_b1     = (const float*)d_in[5];
  const float* msg_w2     = (const float*)d_in[6];
  const float* msg_b2     = (const float*)d_in[7];
  const float* upd_w1     = (const float*)d_in[8];
  const float* upd_b1     = (const float*)d_in[9];
  const float* upd_w2     = (const float*)d_in[10];
  const float* upd_b2     = (const float*)d_in[11];
  const float* ln_g       = (const float*)d_in[12];
  const float* ln_b       = (const float*)d_in[13];

  char* ws = (char*)d_ws;
  unsigned short* agg     = (unsigned short*)(ws + 0);         //  25,600,000 (bf16)
  float* deg              = (float*)(ws + 25600000);           //     400,000
  unsigned short* node_bf = (unsigned short*)(ws + 26000000);  //  25,600,000
  unsigned short* w1b     = (unsigned short*)(ws + 51600000);  //      65,536
  unsigned short* w2b     = (unsigned short*)(ws + 51665536);  //      32,768
  unsigned short* gb      = (unsigned short*)(ws + 51698304);  //         128
  float* h1buf            = (float*)(ws + 51700000);           //  51,200,000
  (void)ws_size; (void)in_sizes; (void)n_in; (void)out_size;

  hipMemsetAsync(ws, 0, 26000000, stream);  // agg (bf16 zeros) + deg
  hipLaunchKernelGGL(convert_kernel, dim3(2048), dim3(256), 0, stream,
                     node_state, msg_w1, msg_w2, gstate, node_bf, w1b, w2b, gb);
  hipLaunchKernelGGL(edge_kernel, dim3(1024), dim3(256), 0, stream,
                     ei, edge_state, node_bf, w1b, w2b, msg_b1, msg_b2, gb, agg, deg);
  hipLaunchKernelGGL(upd1_kernel, dim3((NN + 127) / 128), dim3(128), 0, stream,
                     node_state, agg, deg, upd_w1, upd_b1, gstate, h1buf);
  hipLaunchKernelGGL(upd2_kernel, dim3((NN + 127) / 128), dim3(128), 0, stream,
                     node_state, h1buf, upd_w2, upd_b2, ln_g, ln_b, (float*)d_out);
}

// Round 11
// 1128.182 us; speedup vs baseline: 1.2666x; 1.2666x over previous
//
#include <hip/hip_runtime.h>
#include <hip/hip_bf16.h>
#include <stdint.h>

#define NN 100000
#define NE 1600000
#define EDGE_GRID 512      // proven-best edge concurrency (r3: 772 us)
#define UPDA_BLOCKS 391    // ceil(NN/256)

typedef __attribute__((ext_vector_type(4))) float f32x4;
typedef __attribute__((ext_vector_type(8))) __bf16 bf16x8;
typedef __attribute__((ext_vector_type(8))) short s16x8;
typedef __attribute__((ext_vector_type(4))) unsigned int u32x4;

__device__ __forceinline__ unsigned short f2bf(float f) {
  unsigned int u = __builtin_bit_cast(unsigned int, f);
  u += 0x7fffu + ((u >> 16) & 1u);
  return (unsigned short)(u >> 16);
}

__device__ __forceinline__ f32x4 mfma16(bf16x8 a, bf16x8 b, f32x4 c) {
  return __builtin_amdgcn_mfma_f32_16x16x32_bf16(a, b, c, 0, 0, 0);
}

// ---------------------------------------------------------------------------
// setup: msg weights + global -> bf16
// ---------------------------------------------------------------------------
__global__ void convert_kernel(const float* __restrict__ w1, const float* __restrict__ w2,
                               const float* __restrict__ g,
                               unsigned short* __restrict__ w1b, unsigned short* __restrict__ w2b,
                               unsigned short* __restrict__ gb)
{
  const int tid = blockIdx.x * 256 + threadIdx.x;
  if (tid < 256 * 128) w1b[tid] = f2bf(w1[tid]);
  if (tid < 128 * 128) w2b[tid] = f2bf(w2[tid]);
  if (tid < 64) gb[tid] = f2bf(g[tid]);
}

// ---------------------------------------------------------------------------
// fused kernel, heterogeneous by blockIdx:
//  blocks [0, EDGE_GRID): r3 edge kernel VERBATIM (772 us proven config) --
//    msg-MLP via bf16 MFMA, direct f32 atomic scatter into agg + deg.
//  blocks [EDGE_GRID, EDGE_GRID+UPDA_BLOCKS): updA -- the agg-INDEPENDENT
//    half of upd1 (b1 + node@U1[0:128] + gs@U1[256:320]) running in the
//    edge phase's shadow on idle VALUs. Writes hpart (pre-relu).
// ---------------------------------------------------------------------------
__global__ __launch_bounds__(256, 2) void fused_kernel(
    const int* __restrict__ ei,
    const float* __restrict__ edge_state,
    const float* __restrict__ node_state,
    const unsigned short* __restrict__ w1b,
    const unsigned short* __restrict__ w2b,
    const float* __restrict__ bias1g,
    const float* __restrict__ bias2g,
    const unsigned short* __restrict__ gb,
    float* __restrict__ agg,
    float* __restrict__ deg,
    const float* __restrict__ u1,     // f32 [320][128]
    const float* __restrict__ ub1,
    const float* __restrict__ gs,     // f32 [64]
    float* __restrict__ hpart)
{
  __shared__ unsigned short sX[64 * 256];  // 32 KB
  __shared__ unsigned short sH[64 * 128];  // 16 KB
  __shared__ int sDst[64];

  const int t = threadIdx.x;

  if (blockIdx.x >= EDGE_GRID) {
    // ================= updA: agg-independent half of upd1 =================
    const int n = (blockIdx.x - EDGE_GRID) * 256 + t;
    const bool act = n < NN;
    const size_t row = (size_t)(act ? n : 0) * 128;

    f32x4 acc[32];
#pragma unroll
    for (int c = 0; c < 32; ++c) acc[c] = *(const f32x4*)(ub1 + 4 * c);

    for (int k4 = 0; k4 < 32; ++k4) {          // node part: k = 0..127
      const f32x4 x = *(const f32x4*)(node_state + row + 4 * k4);
#pragma unroll
      for (int kk = 0; kk < 4; ++kk) {
        const float xk = x[kk];
        const float* wr = u1 + (size_t)(4 * k4 + kk) * 128;
#pragma unroll
        for (int c = 0; c < 32; ++c) acc[c] += xk * *(const f32x4*)(wr + 4 * c);
      }
    }
    for (int k = 0; k < 64; ++k) {             // global part: k = 256..319
      const float xk = gs[k];
      const float* wr = u1 + (size_t)(256 + k) * 128;
#pragma unroll
      for (int c = 0; c < 32; ++c) acc[c] += xk * *(const f32x4*)(wr + 4 * c);
    }
    if (act) {
      float* o = hpart + (size_t)n * 128;
#pragma unroll
      for (int c = 0; c < 32; ++c) *(f32x4*)(o + 4 * c) = acc[c];
    }
    return;
  }

  // ======================= edge path (r3 verbatim) ========================
  const int lane = t & 63;
  const int wv = t >> 6;
  const int l15 = lane & 15;
  const int lq = lane >> 4;

  bf16x8 b1f[8][2], b2f[4][2];
  float bs1[2], bs2[2];
  for (int n = 0; n < 2; ++n) {
    const int col = wv * 32 + n * 16 + l15;
    bs1[n] = bias1g[col];
    bs2[n] = bias2g[col];
    for (int ks = 0; ks < 8; ++ks) {
      const int k0 = ks * 32 + lq * 8;
      s16x8 v;
#pragma unroll
      for (int j = 0; j < 8; ++j) v[j] = (short)w1b[(k0 + j) * 128 + col];
      b1f[ks][n] = __builtin_bit_cast(bf16x8, v);
    }
    for (int ks = 0; ks < 4; ++ks) {
      const int k0 = ks * 32 + lq * 8;
      s16x8 v;
#pragma unroll
      for (int j = 0; j < 8; ++j) v[j] = (short)w2b[(k0 + j) * 128 + col];
      b2f[ks][n] = __builtin_bit_cast(bf16x8, v);
    }
  }

  const int r = t >> 2;
  const int p = t & 3;
  const int rs = r & 7;

  for (int tile = blockIdx.x; tile < NE / 64; tile += EDGE_GRID) {
    __syncthreads();
    const int e0 = tile * 64;

    const int src = ei[e0 + r];
    if (p == 0) {
      const int d = ei[NE + e0 + r];
      sDst[r] = d;
      atomicAdd(&deg[d], 1.0f);
    }
    {  // node gather (f32 -> bf16): chunks 0..15
      const f32x4* nsv = (const f32x4*)(node_state + (size_t)src * 128 + p * 32);
#pragma unroll
      for (int j = 0; j < 4; ++j) {
        f32x4 x0 = nsv[2 * j], x1 = nsv[2 * j + 1];
        unsigned short buf[8];
#pragma unroll
        for (int i = 0; i < 4; ++i) { buf[i] = f2bf(x0[i]); buf[4 + i] = f2bf(x1[i]); }
        const int c = p * 4 + j;
        *(u32x4*)((char*)sX + r * 512 + ((c ^ rs) * 16)) = *(u32x4*)buf;
      }
    }
    {  // edge_state: f32 -> bf16, chunks 16..23
      const f32x4* es = (const f32x4*)(edge_state + (size_t)e0 * 64 + r * 64 + p * 16);
      f32x4 e0v = es[0], e1v = es[1], e2v = es[2], e3v = es[3];
      unsigned short bufa[8], bufb[8];
#pragma unroll
      for (int i = 0; i < 4; ++i) {
        bufa[i] = f2bf(e0v[i]); bufa[4 + i] = f2bf(e1v[i]);
        bufb[i] = f2bf(e2v[i]); bufb[4 + i] = f2bf(e3v[i]);
      }
      const int c = 16 + 2 * p;
      *(u32x4*)((char*)sX + r * 512 + ((c ^ rs) * 16)) = *(u32x4*)bufa;
      *(u32x4*)((char*)sX + r * 512 + (((c + 1) ^ rs) * 16)) = *(u32x4*)bufb;
    }
    {  // global (pre-converted bf16): chunks 24..31
      const u32x4* g = (const u32x4*)(gb + p * 16);
      const int c = 24 + 2 * p;
      *(u32x4*)((char*)sX + r * 512 + ((c ^ rs) * 16)) = g[0];
      *(u32x4*)((char*)sX + r * 512 + (((c + 1) ^ rs) * 16)) = g[1];
    }
    __syncthreads();

    // phase 1
    f32x4 acc[4][2];
#pragma unroll
    for (int m = 0; m < 4; ++m)
#pragma unroll
      for (int n = 0; n < 2; ++n)
        acc[m][n] = (f32x4){bs1[n], bs1[n], bs1[n], bs1[n]};
#pragma unroll
    for (int ks = 0; ks < 8; ++ks) {
      bf16x8 a[4];
#pragma unroll
      for (int m = 0; m < 4; ++m) {
        const int row = m * 16 + l15;
        a[m] = *(const bf16x8*)((const char*)sX + row * 512 + (((4 * ks + lq) ^ (row & 7)) * 16));
      }
#pragma unroll
      for (int m = 0; m < 4; ++m)
#pragma unroll
        for (int n = 0; n < 2; ++n)
          acc[m][n] = mfma16(a[m], b1f[ks][n], acc[m][n]);
    }
#pragma unroll
    for (int m = 0; m < 4; ++m)
#pragma unroll
      for (int n = 0; n < 2; ++n)
#pragma unroll
        for (int i = 0; i < 4; ++i) {
          const int row = m * 16 + lq * 4 + i;
          const int col = wv * 32 + n * 16 + l15;
          float v = acc[m][n][i];
          v = v > 0.f ? v : 0.f;
          *(unsigned short*)((char*)sH + row * 256 +
                             ((((col >> 3) ^ (row & 7)) * 16) + (col & 7) * 2)) = f2bf(v);
        }
    __syncthreads();

    // phase 2 + scatter
    f32x4 acc2[4][2];
#pragma unroll
    for (int m = 0; m < 4; ++m)
#pragma unroll
      for (int n = 0; n < 2; ++n)
        acc2[m][n] = (f32x4){bs2[n], bs2[n], bs2[n], bs2[n]};
#pragma unroll
    for (int ks = 0; ks < 4; ++ks) {
      bf16x8 a[4];
#pragma unroll
      for (int m = 0; m < 4; ++m) {
        const int row = m * 16 + l15;
        a[m] = *(const bf16x8*)((const char*)sH + row * 256 + (((4 * ks + lq) ^ (row & 7)) * 16));
      }
#pragma unroll
      for (int m = 0; m < 4; ++m)
#pragma unroll
        for (int n = 0; n < 2; ++n)
          acc2[m][n] = mfma16(a[m], b2f[ks][n], acc2[m][n]);
    }
#pragma unroll
    for (int m = 0; m < 4; ++m)
#pragma unroll
      for (int i = 0; i < 4; ++i) {
        const int row = m * 16 + lq * 4 + i;
        const int d = sDst[row];
#pragma unroll
        for (int n = 0; n < 2; ++n) {
          const int col = wv * 32 + n * 16 + l15;
          atomicAdd(&agg[(size_t)d * 128 + col], acc2[m][n][i]);
        }
      }
  }
}

// ---------------------------------------------------------------------------
// updB: h1 = relu(hpart + (agg/deg) @ U1[128:256])   (the agg-dependent half)
// ---------------------------------------------------------------------------
__global__ __launch_bounds__(128, 3) void updB_kernel(
    const float* __restrict__ hpart,
    const float* __restrict__ agg,
    const float* __restrict__ deg,
    const float* __restrict__ u1,
    float* __restrict__ h1out)
{
  const int n = blockIdx.x * 128 + threadIdx.x;
  const bool act = n < NN;
  const size_t row = (size_t)(act ? n : 0) * 128;

  f32x4 acc[32];
#pragma unroll
  for (int c = 0; c < 32; ++c) acc[c] = *(const f32x4*)(hpart + row + 4 * c);

  const float rdeg = act ? (1.0f / fmaxf(deg[n], 1.0f)) : 0.0f;

  for (int k4 = 0; k4 < 32; ++k4) {
    const f32x4 x = *(const f32x4*)(agg + row + 4 * k4);
#pragma unroll
    for (int kk = 0; kk < 4; ++kk) {
      const float xk = x[kk] * rdeg;
      const float* wr = u1 + (size_t)(128 + 4 * k4 + kk) * 128;
#pragma unroll
      for (int c = 0; c < 32; ++c) acc[c] += xk * *(const f32x4*)(wr + 4 * c);
    }
  }

  if (act) {
    float* o = h1out + (size_t)n * 128;
#pragma unroll
    for (int c = 0; c < 32; ++c) {
      f32x4 v = acc[c];
#pragma unroll
      for (int i = 0; i < 4; ++i) v[i] = v[i] > 0.f ? v[i] : 0.f;
      *(f32x4*)(o + 4 * c) = v;
    }
  }
}

// ---------------------------------------------------------------------------
// update MLP phase 2 + residual + LayerNorm, full f32 (VALU)
// ---------------------------------------------------------------------------
__global__ __launch_bounds__(128, 3) void upd2_kernel(
    const float* __restrict__ node_state,
    const float* __restrict__ h1,
    const float* __restrict__ u2,
    const float* __restrict__ b2,
    const float* __restrict__ lng,
    const float* __restrict__ lnb,
    float* __restrict__ out)
{
  const int n = blockIdx.x * 128 + threadIdx.x;
  const bool act = n < NN;
  const size_t row = (size_t)(act ? n : 0) * 128;

  f32x4 acc[32];
#pragma unroll
  for (int c = 0; c < 32; ++c) acc[c] = *(const f32x4*)(b2 + 4 * c);

  for (int k4 = 0; k4 < 32; ++k4) {
    const f32x4 h = *(const f32x4*)(h1 + row + 4 * k4);
#pragma unroll
    for (int kk = 0; kk < 4; ++kk) {
      const float hk = h[kk];
      const float* wr = u2 + (size_t)(4 * k4 + kk) * 128;
#pragma unroll
      for (int c = 0; c < 32; ++c) acc[c] += hk * *(const f32x4*)(wr + 4 * c);
    }
  }

  if (act) {
    float s = 0.f, s2 = 0.f;
#pragma unroll
    for (int c = 0; c < 32; ++c) {
      const f32x4 nd = *(const f32x4*)(node_state + row + 4 * c);
      f32x4 x = nd + acc[c];
      acc[c] = x;
#pragma unroll
      for (int i = 0; i < 4; ++i) { s += x[i]; s2 += x[i] * x[i]; }
    }
    const float mu = s * (1.0f / 128.0f);
    float var = s2 * (1.0f / 128.0f) - mu * mu;
    var = var < 0.f ? 0.f : var;
    const float rstd = rsqrtf(var + 1e-5f);
    float* o = out + (size_t)n * 128;
#pragma unroll
    for (int c = 0; c < 32; ++c) {
      const f32x4 g = *(const f32x4*)(lng + 4 * c);
      const f32x4 b = *(const f32x4*)(lnb + 4 * c);
      f32x4 x = acc[c];
#pragma unroll
      for (int i = 0; i < 4; ++i) x[i] = (x[i] - mu) * rstd * g[i] + b[i];
      *(f32x4*)(o + 4 * c) = x;
    }
  }
}

// ---------------------------------------------------------------------------
extern "C" void kernel_launch(void* const* d_in, const int* in_sizes, int n_in,
                              void* d_out, int out_size, void* d_ws, size_t ws_size,
                              hipStream_t stream)
{
  const float* node_state = (const float*)d_in[0];
  const int* ei           = (const int*)d_in[1];   // int64 in reference -> int32 from harness
  const float* edge_state = (const float*)d_in[2];
  const float* gstate     = (const float*)d_in[3];
  const float* msg_w1     = (const float*)d_in[4];
  const float* msg_b1     = (const float*)d_in[5];
  const float* msg_w2     = (const float*)d_in[6];
  const float* msg_b2     = (const float*)d_in[7];
  const float* upd_w1     = (const float*)d_in[8];
  const float* upd_b1     = (const float*)d_in[9];
  const float* upd_w2     = (const float*)d_in[10];
  const float* upd_b2     = (const float*)d_in[11];
  const float* ln_g       = (const float*)d_in[12];
  const float* ln_b       = (const float*)d_in[13];

  char* ws = (char*)d_ws;
  float* agg              = (float*)(ws + 0);                  //  51,200,000
  float* deg              = (float*)(ws + 51200000);           //     400,000
  float* hpart            = (float*)(ws + 51600000);           //  51,200,000
  float* h1buf            = (float*)(ws + 102800000);          //  51,200,000
  unsigned short* w1b     = (unsigned short*)(ws + 154000000); //      65,536
  unsigned short* w2b     = (unsigned short*)(ws + 154065536); //      32,768
  unsigned short* gb      = (unsigned short*)(ws + 154098304); //         128
  (void)ws_size; (void)in_sizes; (void)n_in; (void)out_size;

  hipMemsetAsync(ws, 0, 51600000, stream);  // agg + deg
  hipLaunchKernelGGL(convert_kernel, dim3(160), dim3(256), 0, stream,
                     msg_w1, msg_w2, gstate, w1b, w2b, gb);
  hipLaunchKernelGGL(fused_kernel, dim3(EDGE_GRID + UPDA_BLOCKS), dim3(256), 0, stream,
                     ei, edge_state, node_state, w1b, w2b, msg_b1, msg_b2, gb,
                     agg, deg, upd_w1, upd_b1, gstate, hpart);
  hipLaunchKernelGGL(updB_kernel, dim3((NN + 127) / 128), dim3(128), 0, stream,
                     hpart, agg, deg, upd_w1, h1buf);
  hipLaunchKernelGGL(upd2_kernel, dim3((NN + 127) / 128), dim3(128), 0, stream,
                     node_state, h1buf, upd_w2, upd_b2, ln_g, ln_b, (float*)d_out);
}